// Round 1
// baseline (929.175 us; speedup 1.0000x reference)
//
#include <hip/hip_runtime.h>

// ---------------------------------------------------------------------------
// GCN forward: 2x GCNConv(relu) + global_mean_pool + linear
// Strategy: device-built CSR (dst-grouped) reused across both layers;
// transform-first GEMMs with W in LDS; wave-per-node register aggregation;
// run-length pooling over sorted batch ids. All fp32.
// ---------------------------------------------------------------------------

__global__ void k_init(int* __restrict__ cnt, float* __restrict__ psum,
                       float* __restrict__ pcnt, int n, int psumN, int G) {
  int i = blockIdx.x * 256 + threadIdx.x;
  if (i < n) cnt[i] = 0;
  if (i < psumN) psum[i] = 0.f;
  if (i < G) pcnt[i] = 0.f;
}

__global__ void k_count(const int* __restrict__ dst, int* __restrict__ cnt, int E) {
  int i = blockIdx.x * 256 + threadIdx.x;
  if (i < E) atomicAdd(&cnt[dst[i]], 1);
}

__global__ void k_dis(const int* __restrict__ cnt, float* __restrict__ dis, int n) {
  int i = blockIdx.x * 256 + threadIdx.x;
  if (i < n) dis[i] = rsqrtf((float)(cnt[i] + 1));  // +1 self-loop; deg>=1 always
}

// single-block exclusive scan of cnt[0..n) -> rowptr, cursor
__global__ void k_scan(const int* __restrict__ cnt, int* __restrict__ rowptr,
                       int* __restrict__ cursor, int n) {
  __shared__ int sums[1024];
  int t = threadIdx.x;
  int C = (n + 1023) >> 10;
  int lo = t * C, hi = min(lo + C, n);
  int s = 0;
  for (int i = lo; i < hi; ++i) s += cnt[i];
  sums[t] = s;
  __syncthreads();
  for (int off = 1; off < 1024; off <<= 1) {
    int v = (t >= off) ? sums[t - off] : 0;
    __syncthreads();
    sums[t] += v;
    __syncthreads();
  }
  int run = (t == 0) ? 0 : sums[t - 1];
  for (int i = lo; i < hi; ++i) {
    rowptr[i] = run;
    cursor[i] = run;
    run += cnt[i];
  }
}

__global__ void k_build(const int* __restrict__ src, const int* __restrict__ dst,
                        const float* __restrict__ dis, int* __restrict__ cursor,
                        int* __restrict__ esrc, float* __restrict__ enorm, int E) {
  int i = blockIdx.x * 256 + threadIdx.x;
  if (i >= E) return;
  int s = src[i], d = dst[i];
  int slot = atomicAdd(&cursor[d], 1);
  esrc[slot] = s;
  enorm[slot] = dis[s] * dis[d];
}

// out[nrows, COLS] = A[nrows, 128] @ W[128, COLS]; W cached in LDS.
// 64 rows per block, 256 threads, 4-col x RPT-row register tiles.
template <int COLS>
__global__ __launch_bounds__(256) void k_gemm(const float* __restrict__ A,
                                              const float* __restrict__ W,
                                              float* __restrict__ out, int nrows) {
  __shared__ float Ws[128 * COLS];
  int t = threadIdx.x;
  for (int i = t * 4; i < 128 * COLS; i += 1024)
    *(float4*)&Ws[i] = *(const float4*)&W[i];
  __syncthreads();

  constexpr int CG = COLS / 4;   // col groups (32 or 16)
  constexpr int RG = 256 / CG;   // row groups (8 or 16)
  constexpr int RPT = 64 / RG;   // rows per thread (8 or 4)
  int tx = t % CG, ty = t / CG;
  int row0 = blockIdx.x * 64 + ty * RPT;
  int c0 = tx * 4;

  float acc[RPT][4];
#pragma unroll
  for (int r = 0; r < RPT; ++r)
    acc[r][0] = acc[r][1] = acc[r][2] = acc[r][3] = 0.f;

  if (row0 + RPT <= nrows) {
    for (int k = 0; k < 128; k += 4) {
      float4 w0 = *(const float4*)&Ws[(k + 0) * COLS + c0];
      float4 w1 = *(const float4*)&Ws[(k + 1) * COLS + c0];
      float4 w2 = *(const float4*)&Ws[(k + 2) * COLS + c0];
      float4 w3 = *(const float4*)&Ws[(k + 3) * COLS + c0];
#pragma unroll
      for (int r = 0; r < RPT; ++r) {
        float4 a = *(const float4*)&A[(size_t)(row0 + r) * 128 + k];
        acc[r][0] = fmaf(a.x, w0.x, acc[r][0]);
        acc[r][1] = fmaf(a.x, w0.y, acc[r][1]);
        acc[r][2] = fmaf(a.x, w0.z, acc[r][2]);
        acc[r][3] = fmaf(a.x, w0.w, acc[r][3]);
        acc[r][0] = fmaf(a.y, w1.x, acc[r][0]);
        acc[r][1] = fmaf(a.y, w1.y, acc[r][1]);
        acc[r][2] = fmaf(a.y, w1.z, acc[r][2]);
        acc[r][3] = fmaf(a.y, w1.w, acc[r][3]);
        acc[r][0] = fmaf(a.z, w2.x, acc[r][0]);
        acc[r][1] = fmaf(a.z, w2.y, acc[r][1]);
        acc[r][2] = fmaf(a.z, w2.z, acc[r][2]);
        acc[r][3] = fmaf(a.z, w2.w, acc[r][3]);
        acc[r][0] = fmaf(a.w, w3.x, acc[r][0]);
        acc[r][1] = fmaf(a.w, w3.y, acc[r][1]);
        acc[r][2] = fmaf(a.w, w3.z, acc[r][2]);
        acc[r][3] = fmaf(a.w, w3.w, acc[r][3]);
      }
    }
#pragma unroll
    for (int r = 0; r < RPT; ++r)
      *(float4*)&out[(size_t)(row0 + r) * COLS + c0] =
          make_float4(acc[r][0], acc[r][1], acc[r][2], acc[r][3]);
  } else {
    for (int k = 0; k < 128; k += 4) {
      float4 w0 = *(const float4*)&Ws[(k + 0) * COLS + c0];
      float4 w1 = *(const float4*)&Ws[(k + 1) * COLS + c0];
      float4 w2 = *(const float4*)&Ws[(k + 2) * COLS + c0];
      float4 w3 = *(const float4*)&Ws[(k + 3) * COLS + c0];
#pragma unroll
      for (int r = 0; r < RPT; ++r) {
        int row = row0 + r;
        if (row >= nrows) continue;
        float4 a = *(const float4*)&A[(size_t)row * 128 + k];
        acc[r][0] = fmaf(a.x, w0.x, acc[r][0]);
        acc[r][1] = fmaf(a.x, w0.y, acc[r][1]);
        acc[r][2] = fmaf(a.x, w0.z, acc[r][2]);
        acc[r][3] = fmaf(a.x, w0.w, acc[r][3]);
        acc[r][0] = fmaf(a.y, w1.x, acc[r][0]);
        acc[r][1] = fmaf(a.y, w1.y, acc[r][1]);
        acc[r][2] = fmaf(a.y, w1.z, acc[r][2]);
        acc[r][3] = fmaf(a.y, w1.w, acc[r][3]);
        acc[r][0] = fmaf(a.z, w2.x, acc[r][0]);
        acc[r][1] = fmaf(a.z, w2.y, acc[r][1]);
        acc[r][2] = fmaf(a.z, w2.z, acc[r][2]);
        acc[r][3] = fmaf(a.z, w2.w, acc[r][3]);
        acc[r][0] = fmaf(a.w, w3.x, acc[r][0]);
        acc[r][1] = fmaf(a.w, w3.y, acc[r][1]);
        acc[r][2] = fmaf(a.w, w3.z, acc[r][2]);
        acc[r][3] = fmaf(a.w, w3.w, acc[r][3]);
      }
    }
#pragma unroll
    for (int r = 0; r < RPT; ++r)
      if (row0 + r < nrows)
        *(float4*)&out[(size_t)(row0 + r) * COLS + c0] =
            make_float4(acc[r][0], acc[r][1], acc[r][2], acc[r][3]);
  }
}

// one wave per node: out[n] = relu(bias + dis[n]^2*H[n] + sum_e norm_e*H[src_e])
template <int COLS>
__global__ __launch_bounds__(256) void k_agg(const float* __restrict__ H,
                                             const int* __restrict__ rowptr,
                                             const int* __restrict__ rowend,
                                             const int* __restrict__ esrc,
                                             const float* __restrict__ enorm,
                                             const float* __restrict__ dis,
                                             const float* __restrict__ bias,
                                             float* __restrict__ out, int n) {
  constexpr int VEC = COLS / 64;
  int node = (blockIdx.x * 256 + threadIdx.x) >> 6;
  if (node >= n) return;
  int lane = threadIdx.x & 63;
  int c = lane * VEC;
  float dn = dis[node];
  float sw = dn * dn;
  float acc[VEC];
  if constexpr (VEC == 2) {
    float2 h = *(const float2*)&H[(size_t)node * COLS + c];
    acc[0] = h.x * sw;
    acc[1] = h.y * sw;
  } else {
    acc[0] = H[(size_t)node * COLS + c] * sw;
  }
  int beg = rowptr[node], end = rowend[node];
  for (int e = beg; e < end; ++e) {
    int s = esrc[e];
    float wt = enorm[e];
    if constexpr (VEC == 2) {
      float2 h = *(const float2*)&H[(size_t)s * COLS + c];
      acc[0] = fmaf(h.x, wt, acc[0]);
      acc[1] = fmaf(h.y, wt, acc[1]);
    } else {
      acc[0] = fmaf(H[(size_t)s * COLS + c], wt, acc[0]);
    }
  }
#pragma unroll
  for (int v = 0; v < VEC; ++v) {
    float r = acc[v] + bias[c + v];
    out[(size_t)node * COLS + c + v] = fmaxf(r, 0.f);
  }
}

// run-length pooling over sorted batch; 32 nodes per wave, lane = column
__global__ void k_pool(const float* __restrict__ H2, const int* __restrict__ batch,
                       float* __restrict__ psum, float* __restrict__ pcnt, int n) {
  int wv = (blockIdx.x * 256 + threadIdx.x) >> 6;
  int lane = threadIdx.x & 63;
  int start = wv * 32;
  if (start >= n) return;
  int end = min(start + 32, n);
  int curg = batch[start];
  float acc = 0.f;
  int cn = 0;
  for (int i = start; i < end; ++i) {
    int g = batch[i];
    if (g != curg) {
      atomicAdd(&psum[curg * 64 + lane], acc);
      if (lane == 0) atomicAdd(&pcnt[curg], (float)cn);
      acc = 0.f;
      cn = 0;
      curg = g;
    }
    acc += H2[(size_t)i * 64 + lane];
    ++cn;
  }
  atomicAdd(&psum[curg * 64 + lane], acc);
  if (lane == 0) atomicAdd(&pcnt[curg], (float)cn);
}

__global__ void k_final(const float* __restrict__ psum, const float* __restrict__ pcnt,
                        const float* __restrict__ lin_w, const float* __restrict__ lin_b,
                        float* __restrict__ out, int G) {
  int g = blockIdx.x * 64 + threadIdx.x;
  if (g >= G) return;
  float c = fmaxf(pcnt[g], 1.f);
  float s = 0.f;
  for (int i = 0; i < 64; ++i) s += psum[g * 64 + i] * lin_w[i];
  out[g] = s / c + lin_b[0];
}

extern "C" void kernel_launch(void* const* d_in, const int* in_sizes, int n_in,
                              void* d_out, int out_size, void* d_ws, size_t ws_size,
                              hipStream_t stream) {
  const float* x = (const float*)d_in[0];
  const int* edge = (const int*)d_in[1];
  const int* batch = (const int*)d_in[2];
  const float* W1 = (const float*)d_in[3];
  const float* b1 = (const float*)d_in[4];
  const float* W2 = (const float*)d_in[5];
  const float* b2 = (const float*)d_in[6];
  const float* lin_w = (const float*)d_in[7];
  const float* lin_b = (const float*)d_in[8];
  float* out = (float*)d_out;

  const int N = in_sizes[2];
  const int E = in_sizes[1] / 2;
  const int G = out_size;
  const int* esrc_in = edge;       // edge_index[0] = src
  const int* edst_in = edge + E;   // edge_index[1] = dst

  char* w = (char*)d_ws;
  size_t off = 0;
  auto take = [&](size_t bytes) {
    void* p = w + off;
    off += (bytes + 255) & ~(size_t)255;
    return p;
  };
  int* cnt = (int*)take((size_t)N * 4);
  int* rowptr = (int*)take((size_t)N * 4);
  int* cursor = (int*)take((size_t)N * 4);   // after build: cursor[i] == row end
  float* dis = (float*)take((size_t)N * 4);
  int* esrc = (int*)take((size_t)E * 4);
  float* enorm = (float*)take((size_t)E * 4);
  float* XW = (float*)take((size_t)N * 128 * 4);  // also reused as [N,64] for layer 2
  float* H1 = (float*)take((size_t)N * 128 * 4);  // also reused as H2 [N,64]
  float* psum = (float*)take((size_t)G * 64 * 4);
  float* pcnt = (float*)take((size_t)G * 4);
  (void)ws_size;
  (void)n_in;

  int nb_n = (N + 255) / 256;
  int nb_e = (E + 255) / 256;

  k_init<<<nb_n, 256, 0, stream>>>(cnt, psum, pcnt, N, G * 64, G);
  k_count<<<nb_e, 256, 0, stream>>>(edst_in, cnt, E);
  k_dis<<<nb_n, 256, 0, stream>>>(cnt, dis, N);
  k_scan<<<1, 1024, 0, stream>>>(cnt, rowptr, cursor, N);
  k_build<<<nb_e, 256, 0, stream>>>(esrc_in, edst_in, dis, cursor, esrc, enorm, E);

  int gb = (N + 63) / 64;
  int ab = (int)(((size_t)N * 64 + 255) / 256);

  // layer 1: XW = x@W1; H1 = relu(agg(XW) + b1)
  k_gemm<128><<<gb, 256, 0, stream>>>(x, W1, XW, N);
  k_agg<128><<<ab, 256, 0, stream>>>(XW, rowptr, cursor, esrc, enorm, dis, b1, H1, N);

  // layer 2: XW[:, :64] = H1@W2; H2 (into H1 buffer) = relu(agg) + b2
  k_gemm<64><<<gb, 256, 0, stream>>>(H1, W2, XW, N);
  k_agg<64><<<ab, 256, 0, stream>>>(XW, rowptr, cursor, esrc, enorm, dis, b2, H1, N);

  // mean-pool + linear head
  int pb = (int)((((size_t)(N + 31) / 32) * 64 + 255) / 256);
  k_pool<<<pb, 256, 0, stream>>>(H1, batch, psum, pcnt, N);
  k_final<<<1, 64, 0, stream>>>(psum, pcnt, lin_w, lin_b, out, G);
}

// Round 2
// 747.755 us; speedup vs baseline: 1.2426x; 1.2426x over previous
//
#include <hip/hip_runtime.h>

// ---------------------------------------------------------------------------
// GCN forward: 2x GCNConv(relu) + global_mean_pool + linear
// Strategy: device-built CSR (dst-grouped) reused across both layers;
// transform-first GEMMs with W in LDS; wave-per-node register aggregation;
// run-length pooling over sorted batch ids. All fp32.
// R1: single-block scan (232us, 0.15% occupancy) -> 3-phase multi-block scan.
// ---------------------------------------------------------------------------

__global__ void k_init(int* __restrict__ cnt, float* __restrict__ psum,
                       float* __restrict__ pcnt, int n, int psumN, int G) {
  int i = blockIdx.x * 256 + threadIdx.x;
  if (i < n) cnt[i] = 0;
  if (i < psumN) psum[i] = 0.f;
  if (i < G) pcnt[i] = 0.f;
}

__global__ void k_count(const int* __restrict__ dst, int* __restrict__ cnt, int E) {
  int i = blockIdx.x * 256 + threadIdx.x;
  if (i < E) atomicAdd(&cnt[dst[i]], 1);
}

__global__ void k_dis(const int* __restrict__ cnt, float* __restrict__ dis, int n) {
  int i = blockIdx.x * 256 + threadIdx.x;
  if (i < n) dis[i] = rsqrtf((float)(cnt[i] + 1));  // +1 self-loop; deg>=1 always
}

// ---- 3-phase exclusive scan of cnt[0..n) -> rowptr, cursor ---------------
// Phase A: per-block (1024 elems) sum -> bsum[b]
__global__ __launch_bounds__(256) void k_scanA(const int* __restrict__ cnt,
                                               int* __restrict__ bsum, int n) {
  __shared__ int red[256];
  int t = threadIdx.x;
  int base = blockIdx.x * 1024 + t * 4;
  int s = 0;
#pragma unroll
  for (int j = 0; j < 4; ++j) {
    int i = base + j;
    if (i < n) s += cnt[i];
  }
  red[t] = s;
  __syncthreads();
  for (int off = 128; off > 0; off >>= 1) {
    if (t < off) red[t] += red[t + off];
    __syncthreads();
  }
  if (t == 0) bsum[blockIdx.x] = red[0];
}

// Phase B: single small block scans the per-block sums (NB <= 256)
__global__ __launch_bounds__(256) void k_scanB(const int* __restrict__ bsum,
                                               int* __restrict__ boff, int NB) {
  __shared__ int sh[256];
  int t = threadIdx.x;
  sh[t] = (t < NB) ? bsum[t] : 0;
  __syncthreads();
  for (int off = 1; off < 256; off <<= 1) {
    int v = (t >= off) ? sh[t - off] : 0;
    __syncthreads();
    sh[t] += v;
    __syncthreads();
  }
  if (t < NB) boff[t] = (t == 0) ? 0 : sh[t - 1];
}

// Phase C: local exclusive scan + block offset -> rowptr, cursor
__global__ __launch_bounds__(256) void k_scanC(const int* __restrict__ cnt,
                                               const int* __restrict__ boff,
                                               int* __restrict__ rowptr,
                                               int* __restrict__ cursor, int n) {
  __shared__ int sh[256];
  int t = threadIdx.x;
  int base = blockIdx.x * 1024 + t * 4;
  int v[4];
  int s = 0;
#pragma unroll
  for (int j = 0; j < 4; ++j) {
    int i = base + j;
    v[j] = (i < n) ? cnt[i] : 0;
    s += v[j];
  }
  sh[t] = s;
  __syncthreads();
  for (int off = 1; off < 256; off <<= 1) {
    int u = (t >= off) ? sh[t - off] : 0;
    __syncthreads();
    sh[t] += u;
    __syncthreads();
  }
  int run = boff[blockIdx.x] + ((t == 0) ? 0 : sh[t - 1]);
#pragma unroll
  for (int j = 0; j < 4; ++j) {
    int i = base + j;
    if (i < n) {
      rowptr[i] = run;
      cursor[i] = run;
      run += v[j];
    }
  }
}

__global__ void k_build(const int* __restrict__ src, const int* __restrict__ dst,
                        const float* __restrict__ dis, int* __restrict__ cursor,
                        int* __restrict__ esrc, float* __restrict__ enorm, int E) {
  int i = blockIdx.x * 256 + threadIdx.x;
  if (i >= E) return;
  int s = src[i], d = dst[i];
  int slot = atomicAdd(&cursor[d], 1);
  esrc[slot] = s;
  enorm[slot] = dis[s] * dis[d];
}

// out[nrows, COLS] = A[nrows, 128] @ W[128, COLS]; W cached in LDS.
// 64 rows per block, 256 threads, 4-col x RPT-row register tiles.
template <int COLS>
__global__ __launch_bounds__(256) void k_gemm(const float* __restrict__ A,
                                              const float* __restrict__ W,
                                              float* __restrict__ out, int nrows) {
  __shared__ float Ws[128 * COLS];
  int t = threadIdx.x;
  for (int i = t * 4; i < 128 * COLS; i += 1024)
    *(float4*)&Ws[i] = *(const float4*)&W[i];
  __syncthreads();

  constexpr int CG = COLS / 4;   // col groups (32 or 16)
  constexpr int RG = 256 / CG;   // row groups (8 or 16)
  constexpr int RPT = 64 / RG;   // rows per thread (8 or 4)
  int tx = t % CG, ty = t / CG;
  int row0 = blockIdx.x * 64 + ty * RPT;
  int c0 = tx * 4;

  float acc[RPT][4];
#pragma unroll
  for (int r = 0; r < RPT; ++r)
    acc[r][0] = acc[r][1] = acc[r][2] = acc[r][3] = 0.f;

  if (row0 + RPT <= nrows) {
    for (int k = 0; k < 128; k += 4) {
      float4 w0 = *(const float4*)&Ws[(k + 0) * COLS + c0];
      float4 w1 = *(const float4*)&Ws[(k + 1) * COLS + c0];
      float4 w2 = *(const float4*)&Ws[(k + 2) * COLS + c0];
      float4 w3 = *(const float4*)&Ws[(k + 3) * COLS + c0];
#pragma unroll
      for (int r = 0; r < RPT; ++r) {
        float4 a = *(const float4*)&A[(size_t)(row0 + r) * 128 + k];
        acc[r][0] = fmaf(a.x, w0.x, acc[r][0]);
        acc[r][1] = fmaf(a.x, w0.y, acc[r][1]);
        acc[r][2] = fmaf(a.x, w0.z, acc[r][2]);
        acc[r][3] = fmaf(a.x, w0.w, acc[r][3]);
        acc[r][0] = fmaf(a.y, w1.x, acc[r][0]);
        acc[r][1] = fmaf(a.y, w1.y, acc[r][1]);
        acc[r][2] = fmaf(a.y, w1.z, acc[r][2]);
        acc[r][3] = fmaf(a.y, w1.w, acc[r][3]);
        acc[r][0] = fmaf(a.z, w2.x, acc[r][0]);
        acc[r][1] = fmaf(a.z, w2.y, acc[r][1]);
        acc[r][2] = fmaf(a.z, w2.z, acc[r][2]);
        acc[r][3] = fmaf(a.z, w2.w, acc[r][3]);
        acc[r][0] = fmaf(a.w, w3.x, acc[r][0]);
        acc[r][1] = fmaf(a.w, w3.y, acc[r][1]);
        acc[r][2] = fmaf(a.w, w3.z, acc[r][2]);
        acc[r][3] = fmaf(a.w, w3.w, acc[r][3]);
      }
    }
#pragma unroll
    for (int r = 0; r < RPT; ++r)
      *(float4*)&out[(size_t)(row0 + r) * COLS + c0] =
          make_float4(acc[r][0], acc[r][1], acc[r][2], acc[r][3]);
  } else {
    for (int k = 0; k < 128; k += 4) {
      float4 w0 = *(const float4*)&Ws[(k + 0) * COLS + c0];
      float4 w1 = *(const float4*)&Ws[(k + 1) * COLS + c0];
      float4 w2 = *(const float4*)&Ws[(k + 2) * COLS + c0];
      float4 w3 = *(const float4*)&Ws[(k + 3) * COLS + c0];
#pragma unroll
      for (int r = 0; r < RPT; ++r) {
        int row = row0 + r;
        if (row >= nrows) continue;
        float4 a = *(const float4*)&A[(size_t)row * 128 + k];
        acc[r][0] = fmaf(a.x, w0.x, acc[r][0]);
        acc[r][1] = fmaf(a.x, w0.y, acc[r][1]);
        acc[r][2] = fmaf(a.x, w0.z, acc[r][2]);
        acc[r][3] = fmaf(a.x, w0.w, acc[r][3]);
        acc[r][0] = fmaf(a.y, w1.x, acc[r][0]);
        acc[r][1] = fmaf(a.y, w1.y, acc[r][1]);
        acc[r][2] = fmaf(a.y, w1.z, acc[r][2]);
        acc[r][3] = fmaf(a.y, w1.w, acc[r][3]);
        acc[r][0] = fmaf(a.z, w2.x, acc[r][0]);
        acc[r][1] = fmaf(a.z, w2.y, acc[r][1]);
        acc[r][2] = fmaf(a.z, w2.z, acc[r][2]);
        acc[r][3] = fmaf(a.z, w2.w, acc[r][3]);
        acc[r][0] = fmaf(a.w, w3.x, acc[r][0]);
        acc[r][1] = fmaf(a.w, w3.y, acc[r][1]);
        acc[r][2] = fmaf(a.w, w3.z, acc[r][2]);
        acc[r][3] = fmaf(a.w, w3.w, acc[r][3]);
      }
    }
#pragma unroll
    for (int r = 0; r < RPT; ++r)
      if (row0 + r < nrows)
        *(float4*)&out[(size_t)(row0 + r) * COLS + c0] =
            make_float4(acc[r][0], acc[r][1], acc[r][2], acc[r][3]);
  }
}

// one wave per node: out[n] = relu(bias + dis[n]^2*H[n] + sum_e norm_e*H[src_e])
template <int COLS>
__global__ __launch_bounds__(256) void k_agg(const float* __restrict__ H,
                                             const int* __restrict__ rowptr,
                                             const int* __restrict__ rowend,
                                             const int* __restrict__ esrc,
                                             const float* __restrict__ enorm,
                                             const float* __restrict__ dis,
                                             const float* __restrict__ bias,
                                             float* __restrict__ out, int n) {
  constexpr int VEC = COLS / 64;
  int node = (blockIdx.x * 256 + threadIdx.x) >> 6;
  if (node >= n) return;
  int lane = threadIdx.x & 63;
  int c = lane * VEC;
  float dn = dis[node];
  float sw = dn * dn;
  float acc[VEC];
  if constexpr (VEC == 2) {
    float2 h = *(const float2*)&H[(size_t)node * COLS + c];
    acc[0] = h.x * sw;
    acc[1] = h.y * sw;
  } else {
    acc[0] = H[(size_t)node * COLS + c] * sw;
  }
  int beg = rowptr[node], end = rowend[node];
  for (int e = beg; e < end; ++e) {
    int s = esrc[e];
    float wt = enorm[e];
    if constexpr (VEC == 2) {
      float2 h = *(const float2*)&H[(size_t)s * COLS + c];
      acc[0] = fmaf(h.x, wt, acc[0]);
      acc[1] = fmaf(h.y, wt, acc[1]);
    } else {
      acc[0] = fmaf(H[(size_t)s * COLS + c], wt, acc[0]);
    }
  }
#pragma unroll
  for (int v = 0; v < VEC; ++v) {
    float r = acc[v] + bias[c + v];
    out[(size_t)node * COLS + c + v] = fmaxf(r, 0.f);
  }
}

// run-length pooling over sorted batch; 32 nodes per wave, lane = column
__global__ void k_pool(const float* __restrict__ H2, const int* __restrict__ batch,
                       float* __restrict__ psum, float* __restrict__ pcnt, int n) {
  int wv = (blockIdx.x * 256 + threadIdx.x) >> 6;
  int lane = threadIdx.x & 63;
  int start = wv * 32;
  if (start >= n) return;
  int end = min(start + 32, n);
  int curg = batch[start];
  float acc = 0.f;
  int cn = 0;
  for (int i = start; i < end; ++i) {
    int g = batch[i];
    if (g != curg) {
      atomicAdd(&psum[curg * 64 + lane], acc);
      if (lane == 0) atomicAdd(&pcnt[curg], (float)cn);
      acc = 0.f;
      cn = 0;
      curg = g;
    }
    acc += H2[(size_t)i * 64 + lane];
    ++cn;
  }
  atomicAdd(&psum[curg * 64 + lane], acc);
  if (lane == 0) atomicAdd(&pcnt[curg], (float)cn);
}

__global__ void k_final(const float* __restrict__ psum, const float* __restrict__ pcnt,
                        const float* __restrict__ lin_w, const float* __restrict__ lin_b,
                        float* __restrict__ out, int G) {
  int g = blockIdx.x * 64 + threadIdx.x;
  if (g >= G) return;
  float c = fmaxf(pcnt[g], 1.f);
  float s = 0.f;
  for (int i = 0; i < 64; ++i) s += psum[g * 64 + i] * lin_w[i];
  out[g] = s / c + lin_b[0];
}

extern "C" void kernel_launch(void* const* d_in, const int* in_sizes, int n_in,
                              void* d_out, int out_size, void* d_ws, size_t ws_size,
                              hipStream_t stream) {
  const float* x = (const float*)d_in[0];
  const int* edge = (const int*)d_in[1];
  const int* batch = (const int*)d_in[2];
  const float* W1 = (const float*)d_in[3];
  const float* b1 = (const float*)d_in[4];
  const float* W2 = (const float*)d_in[5];
  const float* b2 = (const float*)d_in[6];
  const float* lin_w = (const float*)d_in[7];
  const float* lin_b = (const float*)d_in[8];
  float* out = (float*)d_out;

  const int N = in_sizes[2];
  const int E = in_sizes[1] / 2;
  const int G = out_size;
  const int* esrc_in = edge;       // edge_index[0] = src
  const int* edst_in = edge + E;   // edge_index[1] = dst

  char* w = (char*)d_ws;
  size_t off = 0;
  auto take = [&](size_t bytes) {
    void* p = w + off;
    off += (bytes + 255) & ~(size_t)255;
    return p;
  };
  int* cnt = (int*)take((size_t)N * 4);
  int* rowptr = (int*)take((size_t)N * 4);
  int* cursor = (int*)take((size_t)N * 4);   // after build: cursor[i] == row end
  float* dis = (float*)take((size_t)N * 4);
  int* esrc = (int*)take((size_t)E * 4);
  float* enorm = (float*)take((size_t)E * 4);
  float* XW = (float*)take((size_t)N * 128 * 4);  // also reused as [N,64] for layer 2
  float* H1 = (float*)take((size_t)N * 128 * 4);  // also reused as H2 [N,64]
  float* psum = (float*)take((size_t)G * 64 * 4);
  float* pcnt = (float*)take((size_t)G * 4);
  int* bsum = (int*)take(1024 * 4);
  int* boff = (int*)take(1024 * 4);
  (void)ws_size;
  (void)n_in;

  int nb_n = (N + 255) / 256;
  int nb_e = (E + 255) / 256;
  int NB = (N + 1023) / 1024;  // scan blocks (98 for N=100000; must be <= 256)

  k_init<<<nb_n, 256, 0, stream>>>(cnt, psum, pcnt, N, G * 64, G);
  k_count<<<nb_e, 256, 0, stream>>>(edst_in, cnt, E);
  k_dis<<<nb_n, 256, 0, stream>>>(cnt, dis, N);
  k_scanA<<<NB, 256, 0, stream>>>(cnt, bsum, N);
  k_scanB<<<1, 256, 0, stream>>>(bsum, boff, NB);
  k_scanC<<<NB, 256, 0, stream>>>(cnt, boff, rowptr, cursor, N);
  k_build<<<nb_e, 256, 0, stream>>>(esrc_in, edst_in, dis, cursor, esrc, enorm, E);

  int gb = (N + 63) / 64;
  int ab = (int)(((size_t)N * 64 + 255) / 256);

  // layer 1: XW = x@W1; H1 = relu(agg(XW) + b1)
  k_gemm<128><<<gb, 256, 0, stream>>>(x, W1, XW, N);
  k_agg<128><<<ab, 256, 0, stream>>>(XW, rowptr, cursor, esrc, enorm, dis, b1, H1, N);

  // layer 2: XW[:, :64] = H1@W2; H2 (into H1 buffer) = relu(agg) + b2
  k_gemm<64><<<gb, 256, 0, stream>>>(H1, W2, XW, N);
  k_agg<64><<<ab, 256, 0, stream>>>(XW, rowptr, cursor, esrc, enorm, dis, b2, H1, N);

  // mean-pool + linear head
  int pb = (int)((((size_t)(N + 31) / 32) * 64 + 255) / 256);
  k_pool<<<pb, 256, 0, stream>>>(H1, batch, psum, pcnt, N);
  k_final<<<1, 64, 0, stream>>>(psum, pcnt, lin_w, lin_b, out, G);
}

// Round 3
// 587.296 us; speedup vs baseline: 1.5821x; 1.2732x over previous
//
#include <hip/hip_runtime.h>

// ---------------------------------------------------------------------------
// GCN forward: 2x GCNConv(relu) + global_mean_pool + linear
// Strategy: device-built CSR (dst-grouped) reused across both layers;
// transform-first GEMMs with W in LDS; multi-edge-group wave aggregation;
// run-length pooling over sorted batch ids. All fp32.
// R1: single-block scan (232us) -> 3-phase multi-block scan.
// R2: k_agg latency-bound (171us, 34% HBM, 1 gather in flight/wave) ->
//     COLS/4 lanes per edge-row (float4), 2-4 edge groups/wave, depth-2
//     pipeline => 4-8 gathers in flight per wave.
// ---------------------------------------------------------------------------

__global__ void k_init(int* __restrict__ cnt, float* __restrict__ psum,
                       float* __restrict__ pcnt, int n, int psumN, int G) {
  int i = blockIdx.x * 256 + threadIdx.x;
  if (i < n) cnt[i] = 0;
  if (i < psumN) psum[i] = 0.f;
  if (i < G) pcnt[i] = 0.f;
}

__global__ void k_count(const int* __restrict__ dst, int* __restrict__ cnt, int E) {
  int i = blockIdx.x * 256 + threadIdx.x;
  if (i < E) atomicAdd(&cnt[dst[i]], 1);
}

__global__ void k_dis(const int* __restrict__ cnt, float* __restrict__ dis, int n) {
  int i = blockIdx.x * 256 + threadIdx.x;
  if (i < n) dis[i] = rsqrtf((float)(cnt[i] + 1));  // +1 self-loop; deg>=1 always
}

// ---- 3-phase exclusive scan of cnt[0..n) -> rowptr, cursor ---------------
__global__ __launch_bounds__(256) void k_scanA(const int* __restrict__ cnt,
                                               int* __restrict__ bsum, int n) {
  __shared__ int red[256];
  int t = threadIdx.x;
  int base = blockIdx.x * 1024 + t * 4;
  int s = 0;
#pragma unroll
  for (int j = 0; j < 4; ++j) {
    int i = base + j;
    if (i < n) s += cnt[i];
  }
  red[t] = s;
  __syncthreads();
  for (int off = 128; off > 0; off >>= 1) {
    if (t < off) red[t] += red[t + off];
    __syncthreads();
  }
  if (t == 0) bsum[blockIdx.x] = red[0];
}

__global__ __launch_bounds__(256) void k_scanB(const int* __restrict__ bsum,
                                               int* __restrict__ boff, int NB) {
  __shared__ int sh[256];
  int t = threadIdx.x;
  sh[t] = (t < NB) ? bsum[t] : 0;
  __syncthreads();
  for (int off = 1; off < 256; off <<= 1) {
    int v = (t >= off) ? sh[t - off] : 0;
    __syncthreads();
    sh[t] += v;
    __syncthreads();
  }
  if (t < NB) boff[t] = (t == 0) ? 0 : sh[t - 1];
}

__global__ __launch_bounds__(256) void k_scanC(const int* __restrict__ cnt,
                                               const int* __restrict__ boff,
                                               int* __restrict__ rowptr,
                                               int* __restrict__ cursor, int n) {
  __shared__ int sh[256];
  int t = threadIdx.x;
  int base = blockIdx.x * 1024 + t * 4;
  int v[4];
  int s = 0;
#pragma unroll
  for (int j = 0; j < 4; ++j) {
    int i = base + j;
    v[j] = (i < n) ? cnt[i] : 0;
    s += v[j];
  }
  sh[t] = s;
  __syncthreads();
  for (int off = 1; off < 256; off <<= 1) {
    int u = (t >= off) ? sh[t - off] : 0;
    __syncthreads();
    sh[t] += u;
    __syncthreads();
  }
  int run = boff[blockIdx.x] + ((t == 0) ? 0 : sh[t - 1]);
#pragma unroll
  for (int j = 0; j < 4; ++j) {
    int i = base + j;
    if (i < n) {
      rowptr[i] = run;
      cursor[i] = run;
      run += v[j];
    }
  }
}

__global__ void k_build(const int* __restrict__ src, const int* __restrict__ dst,
                        const float* __restrict__ dis, int* __restrict__ cursor,
                        int* __restrict__ esrc, float* __restrict__ enorm, int E) {
  int i = blockIdx.x * 256 + threadIdx.x;
  if (i >= E) return;
  int s = src[i], d = dst[i];
  int slot = atomicAdd(&cursor[d], 1);
  esrc[slot] = s;
  enorm[slot] = dis[s] * dis[d];
}

// out[nrows, COLS] = A[nrows, 128] @ W[128, COLS]; W cached in LDS.
template <int COLS>
__global__ __launch_bounds__(256) void k_gemm(const float* __restrict__ A,
                                              const float* __restrict__ W,
                                              float* __restrict__ out, int nrows) {
  __shared__ float Ws[128 * COLS];
  int t = threadIdx.x;
  for (int i = t * 4; i < 128 * COLS; i += 1024)
    *(float4*)&Ws[i] = *(const float4*)&W[i];
  __syncthreads();

  constexpr int CG = COLS / 4;   // col groups (32 or 16)
  constexpr int RG = 256 / CG;   // row groups (8 or 16)
  constexpr int RPT = 64 / RG;   // rows per thread (8 or 4)
  int tx = t % CG, ty = t / CG;
  int row0 = blockIdx.x * 64 + ty * RPT;
  int c0 = tx * 4;

  float acc[RPT][4];
#pragma unroll
  for (int r = 0; r < RPT; ++r)
    acc[r][0] = acc[r][1] = acc[r][2] = acc[r][3] = 0.f;

  if (row0 + RPT <= nrows) {
    for (int k = 0; k < 128; k += 4) {
      float4 w0 = *(const float4*)&Ws[(k + 0) * COLS + c0];
      float4 w1 = *(const float4*)&Ws[(k + 1) * COLS + c0];
      float4 w2 = *(const float4*)&Ws[(k + 2) * COLS + c0];
      float4 w3 = *(const float4*)&Ws[(k + 3) * COLS + c0];
#pragma unroll
      for (int r = 0; r < RPT; ++r) {
        float4 a = *(const float4*)&A[(size_t)(row0 + r) * 128 + k];
        acc[r][0] = fmaf(a.x, w0.x, acc[r][0]);
        acc[r][1] = fmaf(a.x, w0.y, acc[r][1]);
        acc[r][2] = fmaf(a.x, w0.z, acc[r][2]);
        acc[r][3] = fmaf(a.x, w0.w, acc[r][3]);
        acc[r][0] = fmaf(a.y, w1.x, acc[r][0]);
        acc[r][1] = fmaf(a.y, w1.y, acc[r][1]);
        acc[r][2] = fmaf(a.y, w1.z, acc[r][2]);
        acc[r][3] = fmaf(a.y, w1.w, acc[r][3]);
        acc[r][0] = fmaf(a.z, w2.x, acc[r][0]);
        acc[r][1] = fmaf(a.z, w2.y, acc[r][1]);
        acc[r][2] = fmaf(a.z, w2.z, acc[r][2]);
        acc[r][3] = fmaf(a.z, w2.w, acc[r][3]);
        acc[r][0] = fmaf(a.w, w3.x, acc[r][0]);
        acc[r][1] = fmaf(a.w, w3.y, acc[r][1]);
        acc[r][2] = fmaf(a.w, w3.z, acc[r][2]);
        acc[r][3] = fmaf(a.w, w3.w, acc[r][3]);
      }
    }
#pragma unroll
    for (int r = 0; r < RPT; ++r)
      *(float4*)&out[(size_t)(row0 + r) * COLS + c0] =
          make_float4(acc[r][0], acc[r][1], acc[r][2], acc[r][3]);
  } else {
    for (int k = 0; k < 128; k += 4) {
      float4 w0 = *(const float4*)&Ws[(k + 0) * COLS + c0];
      float4 w1 = *(const float4*)&Ws[(k + 1) * COLS + c0];
      float4 w2 = *(const float4*)&Ws[(k + 2) * COLS + c0];
      float4 w3 = *(const float4*)&Ws[(k + 3) * COLS + c0];
#pragma unroll
      for (int r = 0; r < RPT; ++r) {
        int row = row0 + r;
        if (row >= nrows) continue;
        float4 a = *(const float4*)&A[(size_t)row * 128 + k];
        acc[r][0] = fmaf(a.x, w0.x, acc[r][0]);
        acc[r][1] = fmaf(a.x, w0.y, acc[r][1]);
        acc[r][2] = fmaf(a.x, w0.z, acc[r][2]);
        acc[r][3] = fmaf(a.x, w0.w, acc[r][3]);
        acc[r][0] = fmaf(a.y, w1.x, acc[r][0]);
        acc[r][1] = fmaf(a.y, w1.y, acc[r][1]);
        acc[r][2] = fmaf(a.y, w1.z, acc[r][2]);
        acc[r][3] = fmaf(a.y, w1.w, acc[r][3]);
        acc[r][0] = fmaf(a.z, w2.x, acc[r][0]);
        acc[r][1] = fmaf(a.z, w2.y, acc[r][1]);
        acc[r][2] = fmaf(a.z, w2.z, acc[r][2]);
        acc[r][3] = fmaf(a.z, w2.w, acc[r][3]);
        acc[r][0] = fmaf(a.w, w3.x, acc[r][0]);
        acc[r][1] = fmaf(a.w, w3.y, acc[r][1]);
        acc[r][2] = fmaf(a.w, w3.z, acc[r][2]);
        acc[r][3] = fmaf(a.w, w3.w, acc[r][3]);
      }
    }
#pragma unroll
    for (int r = 0; r < RPT; ++r)
      if (row0 + r < nrows)
        *(float4*)&out[(size_t)(row0 + r) * COLS + c0] =
            make_float4(acc[r][0], acc[r][1], acc[r][2], acc[r][3]);
  }
}

// wave per node; COLS/4 lanes per edge-row (float4), NG edge groups per wave,
// depth-2 pipeline => 2*NG gathers in flight. Invalid edges: s=0,w=0.
template <int COLS>
__global__ __launch_bounds__(256) void k_agg(const float* __restrict__ H,
                                             const int* __restrict__ rowptr,
                                             const int* __restrict__ rowend,
                                             const int* __restrict__ esrc,
                                             const float* __restrict__ enorm,
                                             const float* __restrict__ dis,
                                             const float* __restrict__ bias,
                                             float* __restrict__ out, int n) {
  constexpr int LPE = COLS / 4;  // lanes per edge-row (32 or 16)
  constexpr int NG = 64 / LPE;   // edge groups per wave (2 or 4)
  int node = (blockIdx.x * 256 + threadIdx.x) >> 6;
  if (node >= n) return;
  int lane = threadIdx.x & 63;
  int group = lane / LPE;
  int c = (lane % LPE) * 4;

  float4 acc = make_float4(0.f, 0.f, 0.f, 0.f);
  int beg = rowptr[node], end = rowend[node];

  int e0 = beg + group;
  int e1 = e0 + NG;
  int s0 = 0, s1 = 0;
  float w0 = 0.f, w1 = 0.f;
  if (e0 < end) { s0 = esrc[e0]; w0 = enorm[e0]; }
  if (e1 < end) { s1 = esrc[e1]; w1 = enorm[e1]; }
  while (e0 < end) {
    float4 h0 = *(const float4*)&H[(size_t)s0 * COLS + c];
    float4 h1 = *(const float4*)&H[(size_t)s1 * COLS + c];
    int e2 = e0 + 2 * NG, e3 = e1 + 2 * NG;
    int s2 = 0, s3 = 0;
    float w2 = 0.f, w3 = 0.f;
    if (e2 < end) { s2 = esrc[e2]; w2 = enorm[e2]; }
    if (e3 < end) { s3 = esrc[e3]; w3 = enorm[e3]; }
    acc.x = fmaf(h0.x, w0, acc.x);
    acc.y = fmaf(h0.y, w0, acc.y);
    acc.z = fmaf(h0.z, w0, acc.z);
    acc.w = fmaf(h0.w, w0, acc.w);
    acc.x = fmaf(h1.x, w1, acc.x);
    acc.y = fmaf(h1.y, w1, acc.y);
    acc.z = fmaf(h1.z, w1, acc.z);
    acc.w = fmaf(h1.w, w1, acc.w);
    e0 = e2; s0 = s2; w0 = w2;
    e1 = e3; s1 = s3; w1 = w3;
  }
  // combine edge groups (lanes with equal lane%LPE)
#pragma unroll
  for (int m = LPE; m < 64; m <<= 1) {
    acc.x += __shfl_xor(acc.x, m, 64);
    acc.y += __shfl_xor(acc.y, m, 64);
    acc.z += __shfl_xor(acc.z, m, 64);
    acc.w += __shfl_xor(acc.w, m, 64);
  }
  if (group == 0) {
    float dn = dis[node];
    float sw = dn * dn;
    float4 hs = *(const float4*)&H[(size_t)node * COLS + c];
    float4 o;
    o.x = fmaxf(fmaf(hs.x, sw, acc.x) + bias[c + 0], 0.f);
    o.y = fmaxf(fmaf(hs.y, sw, acc.y) + bias[c + 1], 0.f);
    o.z = fmaxf(fmaf(hs.z, sw, acc.z) + bias[c + 2], 0.f);
    o.w = fmaxf(fmaf(hs.w, sw, acc.w) + bias[c + 3], 0.f);
    *(float4*)&out[(size_t)node * COLS + c] = o;
  }
}

// run-length pooling over sorted batch; 32 nodes per wave, lane = column
__global__ void k_pool(const float* __restrict__ H2, const int* __restrict__ batch,
                       float* __restrict__ psum, float* __restrict__ pcnt, int n) {
  int wv = (blockIdx.x * 256 + threadIdx.x) >> 6;
  int lane = threadIdx.x & 63;
  int start = wv * 32;
  if (start >= n) return;
  int end = min(start + 32, n);
  int curg = batch[start];
  float acc = 0.f;
  int cn = 0;
  for (int i = start; i < end; ++i) {
    int g = batch[i];
    if (g != curg) {
      atomicAdd(&psum[curg * 64 + lane], acc);
      if (lane == 0) atomicAdd(&pcnt[curg], (float)cn);
      acc = 0.f;
      cn = 0;
      curg = g;
    }
    acc += H2[(size_t)i * 64 + lane];
    ++cn;
  }
  atomicAdd(&psum[curg * 64 + lane], acc);
  if (lane == 0) atomicAdd(&pcnt[curg], (float)cn);
}

__global__ void k_final(const float* __restrict__ psum, const float* __restrict__ pcnt,
                        const float* __restrict__ lin_w, const float* __restrict__ lin_b,
                        float* __restrict__ out, int G) {
  int g = blockIdx.x * 64 + threadIdx.x;
  if (g >= G) return;
  float c = fmaxf(pcnt[g], 1.f);
  float s = 0.f;
  for (int i = 0; i < 64; ++i) s += psum[g * 64 + i] * lin_w[i];
  out[g] = s / c + lin_b[0];
}

extern "C" void kernel_launch(void* const* d_in, const int* in_sizes, int n_in,
                              void* d_out, int out_size, void* d_ws, size_t ws_size,
                              hipStream_t stream) {
  const float* x = (const float*)d_in[0];
  const int* edge = (const int*)d_in[1];
  const int* batch = (const int*)d_in[2];
  const float* W1 = (const float*)d_in[3];
  const float* b1 = (const float*)d_in[4];
  const float* W2 = (const float*)d_in[5];
  const float* b2 = (const float*)d_in[6];
  const float* lin_w = (const float*)d_in[7];
  const float* lin_b = (const float*)d_in[8];
  float* out = (float*)d_out;

  const int N = in_sizes[2];
  const int E = in_sizes[1] / 2;
  const int G = out_size;
  const int* esrc_in = edge;       // edge_index[0] = src
  const int* edst_in = edge + E;   // edge_index[1] = dst

  char* w = (char*)d_ws;
  size_t off = 0;
  auto take = [&](size_t bytes) {
    void* p = w + off;
    off += (bytes + 255) & ~(size_t)255;
    return p;
  };
  int* cnt = (int*)take((size_t)N * 4);
  int* rowptr = (int*)take((size_t)N * 4);
  int* cursor = (int*)take((size_t)N * 4);   // after build: cursor[i] == row end
  float* dis = (float*)take((size_t)N * 4);
  int* esrc = (int*)take((size_t)E * 4);
  float* enorm = (float*)take((size_t)E * 4);
  float* XW = (float*)take((size_t)N * 128 * 4);  // also reused as [N,64] for layer 2
  float* H1 = (float*)take((size_t)N * 128 * 4);  // also reused as H2 [N,64]
  float* psum = (float*)take((size_t)G * 64 * 4);
  float* pcnt = (float*)take((size_t)G * 4);
  int* bsum = (int*)take(1024 * 4);
  int* boff = (int*)take(1024 * 4);
  (void)ws_size;
  (void)n_in;

  int nb_n = (N + 255) / 256;
  int nb_e = (E + 255) / 256;
  int NB = (N + 1023) / 1024;  // scan blocks (98 for N=100000; must be <= 256)

  k_init<<<nb_n, 256, 0, stream>>>(cnt, psum, pcnt, N, G * 64, G);
  k_count<<<nb_e, 256, 0, stream>>>(edst_in, cnt, E);
  k_dis<<<nb_n, 256, 0, stream>>>(cnt, dis, N);
  k_scanA<<<NB, 256, 0, stream>>>(cnt, bsum, N);
  k_scanB<<<1, 256, 0, stream>>>(bsum, boff, NB);
  k_scanC<<<NB, 256, 0, stream>>>(cnt, boff, rowptr, cursor, N);
  k_build<<<nb_e, 256, 0, stream>>>(esrc_in, edst_in, dis, cursor, esrc, enorm, E);

  int gb = (N + 63) / 64;
  int ab = (int)(((size_t)N * 64 + 255) / 256);

  // layer 1: XW = x@W1; H1 = relu(agg(XW) + b1)
  k_gemm<128><<<gb, 256, 0, stream>>>(x, W1, XW, N);
  k_agg<128><<<ab, 256, 0, stream>>>(XW, rowptr, cursor, esrc, enorm, dis, b1, H1, N);

  // layer 2: XW[:, :64] = H1@W2; H2 (into H1 buffer) = relu(agg) + b2
  k_gemm<64><<<gb, 256, 0, stream>>>(H1, W2, XW, N);
  k_agg<64><<<ab, 256, 0, stream>>>(XW, rowptr, cursor, esrc, enorm, dis, b2, H1, N);

  // mean-pool + linear head
  int pb = (int)((((size_t)(N + 31) / 32) * 64 + 255) / 256);
  k_pool<<<pb, 256, 0, stream>>>(H1, batch, psum, pcnt, N);
  k_final<<<1, 64, 0, stream>>>(psum, pcnt, lin_w, lin_b, out, G);
}